// Round 2
// baseline (2527.339 us; speedup 1.0000x reference)
//
#include <hip/hip_runtime.h>
#include <math.h>

#define DIM 256
#define VAL_DIM 300

// att_proj[a][j] = sum_d att_feats[a][d] * W_enc[d][j]; att_score[a] = dot(att_feats[a], a_w[256:512])
__global__ void k_att(const float* __restrict__ att_feats, const float* __restrict__ W_enc,
                      const float* __restrict__ a_w, float* __restrict__ att_proj,
                      float* __restrict__ att_score) {
    int a = blockIdx.x;
    int j = threadIdx.x;
    __shared__ float row[DIM];
    __shared__ float red[DIM];
    float v = att_feats[a * DIM + j];
    row[j] = v;
    red[j] = v * a_w[DIM + j];
    __syncthreads();
    for (int s = 128; s > 0; s >>= 1) {
        if (j < s) red[j] += red[j + s];
        __syncthreads();
    }
    if (j == 0) att_score[a] = red[0];
    float acc = 0.f;
    for (int d = 0; d < DIM; ++d)
        acc += row[d] * W_enc[d * DIM + j];
    att_proj[a * DIM + j] = acc;
}

// val_proj[v][j] = sum_d val_feats[v][d] * W_enc[256+d][j], 4 rows per block
__global__ void k_val(const float* __restrict__ val_feats, const float* __restrict__ W_enc,
                      float* __restrict__ val_proj, int n_val) {
    const int R = 4;
    int base = blockIdx.x * R;
    int j = threadIdx.x;
    __shared__ float rows[R][VAL_DIM];
    for (int t = j; t < R * VAL_DIM; t += DIM) {
        int r = t / VAL_DIM, d = t % VAL_DIM;
        int vr = base + r;
        rows[r][d] = (vr < n_val) ? val_feats[(size_t)vr * VAL_DIM + d] : 0.f;
    }
    __syncthreads();
    float a0 = 0.f, a1 = 0.f, a2 = 0.f, a3 = 0.f;
    for (int d = 0; d < VAL_DIM; ++d) {
        float w = W_enc[(size_t)(DIM + d) * DIM + j];
        a0 += rows[0][d] * w;
        a1 += rows[1][d] * w;
        a2 += rows[2][d] * w;
        a3 += rows[3][d] * w;
    }
    if (base + 0 < n_val) val_proj[(size_t)(base + 0) * DIM + j] = a0;
    if (base + 1 < n_val) val_proj[(size_t)(base + 1) * DIM + j] = a1;
    if (base + 2 < n_val) val_proj[(size_t)(base + 2) * DIM + j] = a2;
    if (base + 3 < n_val) val_proj[(size_t)(base + 3) * DIM + j] = a3;
}

// ent_score[i] = dot(ent_feats[i], a_w[0:256])
__global__ void k_ent_score(const float* __restrict__ ent, const float* __restrict__ a_w,
                            float* __restrict__ score) {
    int i = blockIdx.x;
    int j = threadIdx.x;
    __shared__ float red[DIM];
    red[j] = ent[(size_t)i * DIM + j] * a_w[j];
    __syncthreads();
    for (int s = 128; s > 0; s >>= 1) {
        if (j < s) red[j] += red[j + s];
        __syncthreads();
    }
    if (j == 0) score[i] = red[0];
}

__global__ void k_edge_score(const int* __restrict__ triples, const float* __restrict__ ent_score,
                             const float* __restrict__ att_score, const float* __restrict__ a_b,
                             float* __restrict__ edge_w, float* __restrict__ row_sum, int e_attr) {
    int e = blockIdx.x * blockDim.x + threadIdx.x;
    if (e >= e_attr) return;
    int h = triples[e * 3 + 0];
    int att = triples[e * 3 + 2];
    float s = ent_score[h] + att_score[att] + a_b[0];
    s = (s >= 0.f) ? s : 0.2f * s;  // leaky_relu(0.2)
    float w = expf(s);
    edge_w[e] = w;
    atomicAdd(&row_sum[h], w);
}

// one wave (64 lanes) per edge; lane handles 4 dims
__global__ void k_edge_agg(const int* __restrict__ triples, const float* __restrict__ edge_w,
                           const float* __restrict__ row_sum, const float* __restrict__ att_proj,
                           const float* __restrict__ val_proj, float* __restrict__ agg, int e_attr) {
    int wave = threadIdx.x >> 6;
    int lane = threadIdx.x & 63;
    int e = blockIdx.x * 4 + wave;
    if (e >= e_attr) return;
    int h = triples[e * 3 + 0];
    int val = triples[e * 3 + 1];
    int att = triples[e * 3 + 2];
    float p = edge_w[e] / row_sum[h];
    const float* ap = att_proj + (size_t)att * DIM;
    const float* vp = val_proj + (size_t)val * DIM;
    float* outp = agg + (size_t)h * DIM;
#pragma unroll
    for (int k = 0; k < 4; ++k) {
        int jj = lane + 64 * k;
        atomicAdd(&outp[jj], p * (ap[jj] + vp[jj]));
    }
}

__global__ void k_elu_add(const float* __restrict__ agg, const float* __restrict__ ent,
                          float* __restrict__ F, int n) {
    int idx = blockIdx.x * blockDim.x + threadIdx.x;
    if (idx >= n) return;
    float x = agg[idx] + ent[idx];
    F[idx] = (x > 0.f) ? x : expm1f(x);
}

// rows are sorted (np.unique); binary-search offsets + degree
__global__ void k_deg(const int* __restrict__ rows, int n_edges, int n,
                      int* __restrict__ off, float* __restrict__ deg_inv) {
    int i = blockIdx.x * blockDim.x + threadIdx.x;
    if (i > n) return;
    int lo = 0, hi = n_edges;
    while (lo < hi) {
        int m = (lo + hi) >> 1;
        if (rows[m] < i) lo = m + 1; else hi = m;
    }
    off[i] = lo;
    if (i < n) {
        int lo2 = lo, hi2 = n_edges;
        while (lo2 < hi2) {
            int m = (lo2 + hi2) >> 1;
            if (rows[m] < i + 1) lo2 = m + 1; else hi2 = m;
        }
        int d = lo2 - lo;
        deg_inv[i] = 1.0f / (float)(d > 0 ? d : 1);
    }
}

// T[i][j] = mean over neighbors of F[col][j]
__global__ void k_gcn_agg(const int* __restrict__ off, const int* __restrict__ cols,
                          const float* __restrict__ deg_inv, const float* __restrict__ F,
                          float* __restrict__ T) {
    int i = blockIdx.x;
    int j = threadIdx.x;
    int s = off[i], e = off[i + 1];
    float acc = 0.f;
    for (int k = s; k < e; ++k) {
        int c = cols[k];  // wave-uniform broadcast read
        acc += F[(size_t)c * DIM + j];
    }
    T[(size_t)i * DIM + j] = acc * deg_inv[i];
}

// F[i][j] += act(sum_k T[i][k]*w[k][j] + b[j]); 8 rows per block
template <int ACT>
__global__ void k_gcn_gemm(const float* __restrict__ T, const float* __restrict__ w,
                           const float* __restrict__ b, float* __restrict__ F, int n) {
    const int R = 8;
    int base = blockIdx.x * R;
    int j = threadIdx.x;
    __shared__ float t[R][DIM];
#pragma unroll
    for (int r = 0; r < R; ++r) {
        int i = base + r;
        t[r][j] = (i < n) ? T[(size_t)i * DIM + j] : 0.f;
    }
    __syncthreads();
    float acc[R];
#pragma unroll
    for (int r = 0; r < R; ++r) acc[r] = 0.f;
    for (int k = 0; k < DIM; ++k) {
        float wk = w[k * DIM + j];
#pragma unroll
        for (int r = 0; r < R; ++r) acc[r] += t[r][k] * wk;
    }
    float bb = b[j];
#pragma unroll
    for (int r = 0; r < R; ++r) {
        int i = base + r;
        if (i >= n) continue;
        float h = acc[r] + bb;
        if (ACT) h = (h > 0.f) ? h : 0.f;
        F[(size_t)i * DIM + j] += h;
    }
}

__global__ void k_norm_out(const float* __restrict__ F, float* __restrict__ out) {
    int i = blockIdx.x;
    int j = threadIdx.x;
    __shared__ float red[DIM];
    float v = F[(size_t)i * DIM + j];
    red[j] = v * v;
    __syncthreads();
    for (int s = 128; s > 0; s >>= 1) {
        if (j < s) red[j] += red[j + s];
        __syncthreads();
    }
    float sc = 1.0f / fmaxf(sqrtf(red[0]), 1e-12f);
    out[(size_t)i * DIM + j] = v * sc;
}

__global__ void k_gather(const int* __restrict__ seed, const float* __restrict__ full,
                         float* __restrict__ out) {
    int i = blockIdx.x;
    int j = threadIdx.x;
    out[(size_t)i * DIM + j] = full[(size_t)seed[i] * DIM + j];
}

extern "C" void kernel_launch(void* const* d_in, const int* in_sizes, int n_in,
                              void* d_out, int out_size, void* d_ws, size_t ws_size,
                              hipStream_t stream) {
    const int* seed_sr = (const int*)d_in[0];
    const int* seed_tg = (const int*)d_in[1];
    const int* tri_sr = (const int*)d_in[2];
    const int* tri_tg = (const int*)d_in[3];
    const int* rows_sr = (const int*)d_in[4];
    const int* cols_sr = (const int*)d_in[5];
    const int* rows_tg = (const int*)d_in[6];
    const int* cols_tg = (const int*)d_in[7];
    const float* att_feats = (const float*)d_in[8];
    const float* val_feats = (const float*)d_in[9];
    const float* ent_sr = (const float*)d_in[10];
    const float* ent_tg = (const float*)d_in[11];
    const float* a_w = (const float*)d_in[12];
    const float* a_b = (const float*)d_in[13];
    const float* W_enc = (const float*)d_in[14];
    const float* w1 = (const float*)d_in[15];
    const float* b1 = (const float*)d_in[16];
    const float* w2 = (const float*)d_in[17];
    const float* b2 = (const float*)d_in[18];

    const int N = in_sizes[10] / DIM;        // 50000
    const int n_att = in_sizes[8] / DIM;     // 1001
    const int n_val = in_sizes[9] / VAL_DIM; // 100000
    const int e_attr = in_sizes[2] / 3;      // 200000
    const int n_seed = in_sizes[0];          // 10000

    char* p = (char*)d_ws;
    auto alloc = [&](size_t nbytes) -> void* {
        void* r = (void*)p;
        p += (nbytes + 255) & ~(size_t)255;
        return r;
    };
    float* val_proj = (float*)alloc(sizeof(float) * (size_t)n_val * DIM);
    float* att_proj = (float*)alloc(sizeof(float) * (size_t)n_att * DIM);
    float* att_score = (float*)alloc(sizeof(float) * (size_t)n_att);
    float* ent_score = (float*)alloc(sizeof(float) * (size_t)N);
    float* row_sum = (float*)alloc(sizeof(float) * (size_t)N);
    float* edge_w = (float*)alloc(sizeof(float) * (size_t)e_attr);
    float* deg_inv = (float*)alloc(sizeof(float) * (size_t)N);
    int* off = (int*)alloc(sizeof(int) * (size_t)(N + 1));
    float* F = (float*)alloc(sizeof(float) * (size_t)N * DIM);
    float* T = (float*)alloc(sizeof(float) * (size_t)N * DIM);

    float* out = (float*)d_out;
    float* out_seed_arr[2] = { out, out + (size_t)n_seed * DIM };
    float* out_full_arr[2] = { out + (size_t)2 * n_seed * DIM,
                               out + (size_t)2 * n_seed * DIM + (size_t)N * DIM };

    k_att<<<n_att, DIM, 0, stream>>>(att_feats, W_enc, a_w, att_proj, att_score);
    k_val<<<(n_val + 3) / 4, DIM, 0, stream>>>(val_feats, W_enc, val_proj, n_val);

    const int* tris[2] = { tri_sr, tri_tg };
    const float* ents[2] = { ent_sr, ent_tg };
    const int* rws[2] = { rows_sr, rows_tg };
    const int* cls[2] = { cols_sr, cols_tg };
    const int eadj[2] = { in_sizes[4], in_sizes[6] };
    const int* seeds[2] = { seed_sr, seed_tg };

    for (int s = 0; s < 2; ++s) {
        k_ent_score<<<N, DIM, 0, stream>>>(ents[s], a_w, ent_score);
        hipMemsetAsync(row_sum, 0, sizeof(float) * (size_t)N, stream);
        hipMemsetAsync(T, 0, sizeof(float) * (size_t)N * DIM, stream);
        k_edge_score<<<(e_attr + 255) / 256, 256, 0, stream>>>(tris[s], ent_score, att_score,
                                                               a_b, edge_w, row_sum, e_attr);
        k_edge_agg<<<(e_attr + 3) / 4, 256, 0, stream>>>(tris[s], edge_w, row_sum, att_proj,
                                                         val_proj, T, e_attr);
        k_elu_add<<<(N * DIM + 255) / 256, 256, 0, stream>>>(T, ents[s], F, N * DIM);
        k_deg<<<(N + 1 + 255) / 256, 256, 0, stream>>>(rws[s], eadj[s], N, off, deg_inv);
        k_gcn_agg<<<N, DIM, 0, stream>>>(off, cls[s], deg_inv, F, T);
        k_gcn_gemm<1><<<(N + 7) / 8, DIM, 0, stream>>>(T, w1, b1, F, N);
        k_gcn_agg<<<N, DIM, 0, stream>>>(off, cls[s], deg_inv, F, T);
        k_gcn_gemm<0><<<(N + 7) / 8, DIM, 0, stream>>>(T, w2, b2, F, N);
        k_norm_out<<<N, DIM, 0, stream>>>(F, out_full_arr[s]);
        k_gather<<<n_seed, DIM, 0, stream>>>(seeds[s], out_full_arr[s], out_seed_arr[s]);
    }
}

// Round 3
// 1682.505 us; speedup vs baseline: 1.5021x; 1.5021x over previous
//
#include <hip/hip_runtime.h>
#include <math.h>

#define DIM 256
#define VAL_DIM 300

typedef __attribute__((ext_vector_type(8))) short short8;
typedef __attribute__((ext_vector_type(4))) float fx4;

__device__ __forceinline__ short f2bf(float x) {
    unsigned u = __float_as_uint(x);
    unsigned r = (u + 0x7fff + ((u >> 16) & 1)) >> 16;
    return (short)r;
}
__device__ __forceinline__ float bf2f(short h) {
    return __uint_as_float(((unsigned)(unsigned short)h) << 16);
}

// ---------------- split B (weights) into MFMA B-fragment order, hi/lo bf16 ----------------
// B-frag layout: lane holds B[k = kt*32 + (lane>>4)*8 + j][n = nt*16 + (lane&15)], j=0..7
// storage: frag_idx = nt*(Kp/32) + kt; addr = frag_idx*512 + lane*8 + j
__global__ void k_split_b(const float* __restrict__ W, short* __restrict__ Bhi,
                          short* __restrict__ Blo, int Kreal, int Kp, int Ncols) {
    int idx = blockIdx.x * 256 + threadIdx.x;
    int total = (Ncols / 16) * (Kp / 32) * 64;
    if (idx >= total) return;
    int lane = idx & 63;
    int kt = (idx >> 6) % (Kp / 32);
    int nt = (idx >> 6) / (Kp / 32);
    int n = nt * 16 + (lane & 15);
    int kbase = kt * 32 + ((lane >> 4) & 3) * 8;
    short h[8], l[8];
#pragma unroll
    for (int j = 0; j < 8; ++j) {
        int k = kbase + j;
        float x = (k < Kreal) ? W[(size_t)k * Ncols + n] : 0.f;
        short hh = f2bf(x);
        float r = x - bf2f(hh);
        h[j] = hh;
        l[j] = f2bf(r);
    }
    size_t base = (size_t)idx * 8;
#pragma unroll
    for (int j = 0; j < 8; ++j) { Bhi[base + j] = h[j]; Blo[base + j] = l[j]; }
}

// ---------------- split-bf16 MFMA GEMM: Out = A(MxK fp32) @ B(KxN via frags) ----------------
// MODE 0: Out[row*ldout+col] = acc          (val_proj)
// MODE 1: Out += relu(acc + bias)           (gcn layer 1)
// MODE 2: Out += (acc + bias)               (gcn layer 2)
template <int MODE>
__global__ void k_gemm(const float* __restrict__ A, const short* __restrict__ Bhi,
                       const short* __restrict__ Blo, const float* __restrict__ bias,
                       float* __restrict__ Out, int M, int K, int Kp, int ldout) {
    __shared__ short Ah[8 * 512];  // 8 tiles of (64 lanes x 8 bf16) = 8KB
    __shared__ short Al[8 * 512];
    const int m0 = blockIdx.x * 64;
    const int n0 = blockIdx.y * 64;
    const int tid = threadIdx.x;
    const int wave = tid >> 6;
    const int lane = tid & 63;
    const int wm = (wave >> 1) * 2;  // mtile base (16-row units) for this wave
    const int wn = (wave & 1) * 2;   // ntile base
    fx4 acc[2][2] = {};

    for (int pk = 0; pk < Kp; pk += 64) {
        // ---- stage A panel (64 rows x 64 k) as hi/lo fragments ----
#pragma unroll
        for (int q = 0; q < 2; ++q) {
            int ss = tid + 256 * q;     // 0..511
            int mt = ss >> 7;           // 0..3
            int ks = (ss >> 6) & 1;     // 0..1
            int ln = ss & 63;
            int row = m0 + mt * 16 + (ln & 15);
            int kk = pk + ks * 32 + ((ln >> 4) & 3) * 8;
            float v[8];
            if (row < M && kk + 8 <= K) {
                fx4 u0 = *(const fx4*)&A[(size_t)row * K + kk];
                fx4 u1 = *(const fx4*)&A[(size_t)row * K + kk + 4];
                v[0] = u0[0]; v[1] = u0[1]; v[2] = u0[2]; v[3] = u0[3];
                v[4] = u1[0]; v[5] = u1[1]; v[6] = u1[2]; v[7] = u1[3];
            } else {
#pragma unroll
                for (int j = 0; j < 8; ++j)
                    v[j] = (row < M && kk + j < K) ? A[(size_t)row * K + kk + j] : 0.f;
            }
            short8 h8, l8;
#pragma unroll
            for (int j = 0; j < 8; ++j) {
                short hh = f2bf(v[j]);
                h8[j] = hh;
                l8[j] = f2bf(v[j] - bf2f(hh));
            }
            *(short8*)&Ah[(mt * 2 + ks) * 512 + ln * 8] = h8;
            *(short8*)&Al[(mt * 2 + ks) * 512 + ln * 8] = l8;
        }
        __syncthreads();
        // ---- compute: 2 MFMA k-steps of 32 ----
#pragma unroll
        for (int ks = 0; ks < 2; ++ks) {
            int kglob = pk + ks * 32;
            short8 ah[2], al[2], bh[2], bl[2];
#pragma unroll
            for (int t = 0; t < 2; ++t) {
                ah[t] = *(short8*)&Ah[((wm + t) * 2 + ks) * 512 + lane * 8];
                al[t] = *(short8*)&Al[((wm + t) * 2 + ks) * 512 + lane * 8];
                int ntg = (n0 >> 4) + wn + t;
                size_t fb = ((size_t)(ntg * (Kp >> 5) + (kglob >> 5))) * 512 + lane * 8;
                bh[t] = *(const short8*)&Bhi[fb];
                bl[t] = *(const short8*)&Blo[fb];
            }
#pragma unroll
            for (int i = 0; i < 2; ++i)
#pragma unroll
                for (int j = 0; j < 2; ++j) {
                    acc[i][j] = __builtin_amdgcn_mfma_f32_16x16x32_bf16(ah[i], bh[j], acc[i][j], 0, 0, 0);
                    acc[i][j] = __builtin_amdgcn_mfma_f32_16x16x32_bf16(ah[i], bl[j], acc[i][j], 0, 0, 0);
                    acc[i][j] = __builtin_amdgcn_mfma_f32_16x16x32_bf16(al[i], bh[j], acc[i][j], 0, 0, 0);
                }
        }
        __syncthreads();
    }
    // ---- epilogue: C/D layout col=lane&15, row=quad*4+reg ----
    const int quad = lane >> 4;
    const int cl = lane & 15;
#pragma unroll
    for (int i = 0; i < 2; ++i) {
        int rbase = m0 + (wm + i) * 16 + quad * 4;
#pragma unroll
        for (int j = 0; j < 2; ++j) {
            int col = n0 + (wn + j) * 16 + cl;
            float bb = (MODE == 0) ? 0.f : bias[col];
#pragma unroll
            for (int r = 0; r < 4; ++r) {
                int row = rbase + r;
                if (row >= M) continue;
                if (MODE == 0) {
                    Out[(size_t)row * ldout + col] = acc[i][j][r];
                } else {
                    float h = acc[i][j][r] + bb;
                    if (MODE == 1) h = fmaxf(h, 0.f);
                    Out[(size_t)row * ldout + col] += h;
                }
            }
        }
    }
}

// ---------------- attributed encoder pieces ----------------
__global__ void k_att(const float* __restrict__ att_feats, const float* __restrict__ W_enc,
                      const float* __restrict__ a_w, float* __restrict__ att_proj,
                      float* __restrict__ att_score) {
    int a = blockIdx.x;
    int j = threadIdx.x;
    __shared__ float row[DIM];
    __shared__ float red[DIM];
    float v = att_feats[a * DIM + j];
    row[j] = v;
    red[j] = v * a_w[DIM + j];
    __syncthreads();
    for (int s = 128; s > 0; s >>= 1) {
        if (j < s) red[j] += red[j + s];
        __syncthreads();
    }
    if (j == 0) att_score[a] = red[0];
    float acc = 0.f;
    for (int d = 0; d < DIM; ++d)
        acc += row[d] * W_enc[d * DIM + j];
    att_proj[a * DIM + j] = acc;
}

__global__ void k_ent_score(const float* __restrict__ ent, const float* __restrict__ a_w,
                            float* __restrict__ score) {
    int i = blockIdx.x;
    int j = threadIdx.x;
    __shared__ float red[DIM];
    red[j] = ent[(size_t)i * DIM + j] * a_w[j];
    __syncthreads();
    for (int s = 128; s > 0; s >>= 1) {
        if (j < s) red[j] += red[j + s];
        __syncthreads();
    }
    if (j == 0) score[i] = red[0];
}

__global__ void k_edge_score(const int* __restrict__ triples, const float* __restrict__ ent_score,
                             const float* __restrict__ att_score, const float* __restrict__ a_b,
                             float* __restrict__ edge_w, float* __restrict__ row_sum, int e_attr) {
    int e = blockIdx.x * blockDim.x + threadIdx.x;
    if (e >= e_attr) return;
    int h = triples[e * 3 + 0];
    int att = triples[e * 3 + 2];
    float s = ent_score[h] + att_score[att] + a_b[0];
    s = (s >= 0.f) ? s : 0.2f * s;
    float w = expf(s);
    edge_w[e] = w;
    atomicAdd(&row_sum[h], w);
}

__global__ void k_edge_agg(const int* __restrict__ triples, const float* __restrict__ edge_w,
                           const float* __restrict__ row_sum, const float* __restrict__ att_proj,
                           const float* __restrict__ val_proj, float* __restrict__ agg, int e_attr) {
    int wave = threadIdx.x >> 6;
    int lane = threadIdx.x & 63;
    int e = blockIdx.x * 4 + wave;
    if (e >= e_attr) return;
    int h = triples[e * 3 + 0];
    int val = triples[e * 3 + 1];
    int att = triples[e * 3 + 2];
    float p = edge_w[e] / row_sum[h];
    const float* ap = att_proj + (size_t)att * DIM;
    const float* vp = val_proj + (size_t)val * DIM;
    float* outp = agg + (size_t)h * DIM;
#pragma unroll
    for (int k = 0; k < 4; ++k) {
        int jj = lane + 64 * k;
        atomicAdd(&outp[jj], p * (ap[jj] + vp[jj]));
    }
}

__global__ void k_elu_add(const fx4* __restrict__ agg, const fx4* __restrict__ ent,
                          fx4* __restrict__ F, int n4) {
    int idx = blockIdx.x * blockDim.x + threadIdx.x;
    if (idx >= n4) return;
    fx4 x = agg[idx] + ent[idx];
    fx4 r;
#pragma unroll
    for (int c = 0; c < 4; ++c) r[c] = (x[c] > 0.f) ? x[c] : expm1f(x[c]);
    F[idx] = r;
}

__global__ void k_deg(const int* __restrict__ rows, int n_edges, int n,
                      int* __restrict__ off, float* __restrict__ deg_inv) {
    int i = blockIdx.x * blockDim.x + threadIdx.x;
    if (i > n) return;
    int lo = 0, hi = n_edges;
    while (lo < hi) {
        int m = (lo + hi) >> 1;
        if (rows[m] < i) lo = m + 1; else hi = m;
    }
    off[i] = lo;
    if (i < n) {
        int lo2 = lo, hi2 = n_edges;
        while (lo2 < hi2) {
            int m = (lo2 + hi2) >> 1;
            if (rows[m] < i + 1) lo2 = m + 1; else hi2 = m;
        }
        int d = lo2 - lo;
        deg_inv[i] = 1.0f / (float)(d > 0 ? d : 1);
    }
}

// one wave per row, float4 lanes
__global__ void k_gcn_agg(const int* __restrict__ off, const int* __restrict__ cols,
                          const float* __restrict__ deg_inv, const fx4* __restrict__ F,
                          fx4* __restrict__ T, int n) {
    int wave = threadIdx.x >> 6;
    int lane = threadIdx.x & 63;
    int i = blockIdx.x * 4 + wave;
    if (i >= n) return;
    int s = off[i], e = off[i + 1];
    fx4 acc = {};
    for (int k = s; k < e; ++k) {
        int c = cols[k];
        acc += F[(size_t)c * 64 + lane];
    }
    T[(size_t)i * 64 + lane] = acc * deg_inv[i];
}

__global__ void k_norm_out(const float* __restrict__ F, float* __restrict__ out) {
    int i = blockIdx.x;
    int j = threadIdx.x;
    __shared__ float red[DIM];
    float v = F[(size_t)i * DIM + j];
    red[j] = v * v;
    __syncthreads();
    for (int s = 128; s > 0; s >>= 1) {
        if (j < s) red[j] += red[j + s];
        __syncthreads();
    }
    float sc = 1.0f / fmaxf(sqrtf(red[0]), 1e-12f);
    out[(size_t)i * DIM + j] = v * sc;
}

__global__ void k_gather(const int* __restrict__ seed, const float* __restrict__ full,
                         float* __restrict__ out) {
    int i = blockIdx.x;
    int j = threadIdx.x;
    out[(size_t)i * DIM + j] = full[(size_t)seed[i] * DIM + j];
}

extern "C" void kernel_launch(void* const* d_in, const int* in_sizes, int n_in,
                              void* d_out, int out_size, void* d_ws, size_t ws_size,
                              hipStream_t stream) {
    const int* seed_sr = (const int*)d_in[0];
    const int* seed_tg = (const int*)d_in[1];
    const int* tri_sr = (const int*)d_in[2];
    const int* tri_tg = (const int*)d_in[3];
    const int* rows_sr = (const int*)d_in[4];
    const int* cols_sr = (const int*)d_in[5];
    const int* rows_tg = (const int*)d_in[6];
    const int* cols_tg = (const int*)d_in[7];
    const float* att_feats = (const float*)d_in[8];
    const float* val_feats = (const float*)d_in[9];
    const float* ent_sr = (const float*)d_in[10];
    const float* ent_tg = (const float*)d_in[11];
    const float* a_w = (const float*)d_in[12];
    const float* a_b = (const float*)d_in[13];
    const float* W_enc = (const float*)d_in[14];
    const float* w1 = (const float*)d_in[15];
    const float* b1 = (const float*)d_in[16];
    const float* w2 = (const float*)d_in[17];
    const float* b2 = (const float*)d_in[18];

    const int N = in_sizes[10] / DIM;        // 50000
    const int n_att = in_sizes[8] / DIM;     // 1001
    const int n_val = in_sizes[9] / VAL_DIM; // 100000
    const int e_attr = in_sizes[2] / 3;      // 200000
    const int n_seed = in_sizes[0];          // 10000
    const int KpV = 320;                     // padded K for val gemm

    char* p = (char*)d_ws;
    auto alloc = [&](size_t nbytes) -> void* {
        void* r = (void*)p;
        p += (nbytes + 255) & ~(size_t)255;
        return r;
    };
    float* val_proj = (float*)alloc(sizeof(float) * (size_t)n_val * DIM);
    float* att_proj = (float*)alloc(sizeof(float) * (size_t)n_att * DIM);
    float* att_score = (float*)alloc(sizeof(float) * (size_t)n_att);
    float* ent_score = (float*)alloc(sizeof(float) * (size_t)N);
    float* row_sum = (float*)alloc(sizeof(float) * (size_t)N);
    float* edge_w = (float*)alloc(sizeof(float) * (size_t)e_attr);
    float* deg_inv = (float*)alloc(sizeof(float) * (size_t)N);
    int* off = (int*)alloc(sizeof(int) * (size_t)(N + 1));
    float* F = (float*)alloc(sizeof(float) * (size_t)N * DIM);
    float* T = (float*)alloc(sizeof(float) * (size_t)N * DIM);
    // bf16-split weights in B-frag order
    short* wencv_hi = (short*)alloc(sizeof(short) * (DIM / 16) * (KpV / 32) * 512);
    short* wencv_lo = (short*)alloc(sizeof(short) * (DIM / 16) * (KpV / 32) * 512);
    short* w1_hi = (short*)alloc(sizeof(short) * (DIM / 16) * (DIM / 32) * 512);
    short* w1_lo = (short*)alloc(sizeof(short) * (DIM / 16) * (DIM / 32) * 512);
    short* w2_hi = (short*)alloc(sizeof(short) * (DIM / 16) * (DIM / 32) * 512);
    short* w2_lo = (short*)alloc(sizeof(short) * (DIM / 16) * (DIM / 32) * 512);

    float* out = (float*)d_out;
    float* out_seed_arr[2] = { out, out + (size_t)n_seed * DIM };
    float* out_full_arr[2] = { out + (size_t)2 * n_seed * DIM,
                               out + (size_t)2 * n_seed * DIM + (size_t)N * DIM };

    // weight splits (once)
    {
        int tot_v = (DIM / 16) * (KpV / 32) * 64;
        k_split_b<<<(tot_v + 255) / 256, 256, 0, stream>>>(W_enc + (size_t)DIM * DIM, wencv_hi,
                                                           wencv_lo, VAL_DIM, KpV, DIM);
        int tot_w = (DIM / 16) * (DIM / 32) * 64;
        k_split_b<<<(tot_w + 255) / 256, 256, 0, stream>>>(w1, w1_hi, w1_lo, DIM, DIM, DIM);
        k_split_b<<<(tot_w + 255) / 256, 256, 0, stream>>>(w2, w2_hi, w2_lo, DIM, DIM, DIM);
    }

    k_att<<<n_att, DIM, 0, stream>>>(att_feats, W_enc, a_w, att_proj, att_score);
    // val_proj = val_feats @ W_enc[256:]
    {
        dim3 g((n_val + 63) / 64, DIM / 64);
        k_gemm<0><<<g, 256, 0, stream>>>(val_feats, wencv_hi, wencv_lo, nullptr, val_proj,
                                         n_val, VAL_DIM, KpV, DIM);
    }

    const int* tris[2] = { tri_sr, tri_tg };
    const float* ents[2] = { ent_sr, ent_tg };
    const int* rws[2] = { rows_sr, rows_tg };
    const int* cls[2] = { cols_sr, cols_tg };
    const int eadj[2] = { in_sizes[4], in_sizes[6] };
    const int* seeds[2] = { seed_sr, seed_tg };

    for (int s = 0; s < 2; ++s) {
        k_ent_score<<<N, DIM, 0, stream>>>(ents[s], a_w, ent_score);
        hipMemsetAsync(row_sum, 0, sizeof(float) * (size_t)N, stream);
        hipMemsetAsync(T, 0, sizeof(float) * (size_t)N * DIM, stream);
        k_edge_score<<<(e_attr + 255) / 256, 256, 0, stream>>>(tris[s], ent_score, att_score,
                                                               a_b, edge_w, row_sum, e_attr);
        k_edge_agg<<<(e_attr + 3) / 4, 256, 0, stream>>>(tris[s], edge_w, row_sum, att_proj,
                                                         val_proj, T, e_attr);
        k_elu_add<<<(N * DIM / 4 + 255) / 256, 256, 0, stream>>>((const fx4*)T, (const fx4*)ents[s],
                                                                 (fx4*)F, N * DIM / 4);
        k_deg<<<(N + 1 + 255) / 256, 256, 0, stream>>>(rws[s], eadj[s], N, off, deg_inv);
        dim3 gg((N + 63) / 64, DIM / 64);
        k_gcn_agg<<<(N + 3) / 4, 256, 0, stream>>>(off, cls[s], deg_inv, (const fx4*)F, (fx4*)T, N);
        k_gemm<1><<<gg, 256, 0, stream>>>(T, w1_hi, w1_lo, b1, F, N, DIM, DIM, DIM);
        k_gcn_agg<<<(N + 3) / 4, 256, 0, stream>>>(off, cls[s], deg_inv, (const fx4*)F, (fx4*)T, N);
        k_gemm<2><<<gg, 256, 0, stream>>>(T, w2_hi, w2_lo, b2, F, N, DIM, DIM, DIM);
        k_norm_out<<<N, DIM, 0, stream>>>(F, out_full_arr[s]);
        k_gather<<<n_seed, DIM, 0, stream>>>(seeds[s], out_full_arr[s], out_seed_arr[s]);
    }
}